// Round 2
// baseline (511.195 us; speedup 1.0000x reference)
//
#include <hip/hip_runtime.h>
#include <hip/hip_bf16.h>
#include <stdint.h>

// ---------------------------------------------------------------------------
// VarianceAdaptor. Round 2: barrier-free K-loop.
// conv1d(k=3) GEMM fragments (A and B) are loaded DIRECTLY global->VGPR with
// per-lane addresses; all k-displacements fold into load-offset immediates.
// No LDS / no __syncthreads in the K-loop -> pure register pipeline; L1/L2
// serve the reuse (4 waves share A lines, adjacent blocks share B lines).
// Conv edge taps: scratch buffers have 512B guard bands (reads stay in the
// d_out allocation) and the 2 boundary fragments are cndmask-zeroed.
// ---------------------------------------------------------------------------

typedef __bf16 bf16;
typedef __attribute__((ext_vector_type(8))) __bf16 bf16x8;
typedef __attribute__((ext_vector_type(4))) float f32x4;

#define TSEQ 1024
#define NROWS 32768

// output chunk offsets (floats)
#define O1 33554432          // pitch_pred
#define O2 33587200          // energy_pred
#define O3 33619968          // log_dur
#define O4 33652736          // duration passthrough
#define O5 33685504          // mel_len
#define O6 33685536          // mel_mask

// scratch byte offsets inside d_out (512B guard before xb for t=-1 reads)
#define XB_OFF 512
#define H1B_OFF (XB_OFF + 16777216)          // 3 x 16.77 MB
#define H1B_SZ 16777216
#define WT_OFF (H1B_OFF + 3 * H1B_SZ)        // abuts h1b end; 6 x 384 KB
#define WT_SZ 393216

// ws byte offsets
#define CUM_OFF 0
#define ADDROW_OFF 131072

// ---------------------------------------------------------------------------
// fp32 -> bf16 copy of x (plain row-major, 256 ch/row).
__global__ __launch_bounds__(256) void k_cvt_x(const float* __restrict__ x,
                                               bf16* __restrict__ xb) {
  int t = blockIdx.x * 256 + threadIdx.x;   // 1,048,576 threads
  int g = t >> 5;                           // row 0..32767
  int u = t & 31;                           // 16B unit within row
  const float4* s = (const float4*)(x + ((size_t)g << 8) + (u << 3));
  float4 a = s[0], b = s[1];
  bf16x8 o;
  o[0] = (bf16)a.x; o[1] = (bf16)a.y; o[2] = (bf16)a.z; o[3] = (bf16)a.w;
  o[4] = (bf16)b.x; o[5] = (bf16)b.y; o[6] = (bf16)b.z; o[7] = (bf16)b.w;
  *(bf16x8*)(xb + ((size_t)g << 8) + (u << 3)) = o;
}

// (3,K,H,F) WIO fp32 -> wT[m][f][k] bf16 (k = dt*256 + c), plain.
__global__ __launch_bounds__(256) void k_cvt_w(const float* __restrict__ w1,
                                               const float* __restrict__ w2,
                                               bf16* __restrict__ wt) {
  int f = blockIdx.x * 64 + (threadIdx.x & 63);
  int u = blockIdx.y * 4 + (threadIdx.x >> 6);   // 0..95 (16B unit along k)
  int m = blockIdx.z;                            // 0..5
  const float* W = (m < 3) ? w1 : w2;
  int i = (m < 3) ? m : m - 3;
  int dt = u >> 5;
  int c0 = (u & 31) << 3;
  const float* src = W + (((size_t)(i * 3 + dt) * 256 + c0) << 8) + f;
  bf16x8 o;
#pragma unroll
  for (int cc = 0; cc < 8; ++cc) o[cc] = (bf16)src[(size_t)cc << 8];
  *(bf16x8*)(wt + (size_t)m * 196608 + (size_t)f * 768 + (u << 3)) = o;
}

// cumsum(dur) per batch + mel_len + duration passthrough.
__global__ __launch_bounds__(256) void k_scan(const int* __restrict__ dur,
                                              const int* __restrict__ maxlen,
                                              float* __restrict__ out,
                                              int* __restrict__ cum) {
  int b = blockIdx.x, tid = threadIdx.x;
  __shared__ int lds[256];
  int4 d = ((const int4*)(dur + b * 1024))[tid];
  int p0 = d.x, p1 = p0 + d.y, p2 = p1 + d.z, p3 = p2 + d.w;
  int val = p3;
  lds[tid] = val;
  __syncthreads();
  for (int off = 1; off < 256; off <<= 1) {
    int t = (tid >= off) ? lds[tid - off] : 0;
    __syncthreads();
    val += t;
    lds[tid] = val;
    __syncthreads();
  }
  int excl = val - p3;
  int4 c;
  c.x = excl + p0; c.y = excl + p1; c.z = excl + p2; c.w = excl + p3;
  ((int4*)(cum + b * 1024))[tid] = c;
  float4 fd;
  fd.x = (float)d.x; fd.y = (float)d.y; fd.z = (float)d.z; fd.w = (float)d.w;
  ((float4*)(out + O4 + b * 1024))[tid] = fd;
  if (tid == 255) {
    int mel = val < maxlen[0] ? val : maxlen[0];
    out[O5 + b] = (float)mel;
  }
}

// searchsorted(left) of pitch/energy targets into bins; pack indices.
__global__ __launch_bounds__(256) void k_bins(const float* __restrict__ pt,
                                              const float* __restrict__ et,
                                              const float* __restrict__ pbins,
                                              const float* __restrict__ ebins,
                                              int* __restrict__ addrow) {
  __shared__ float pb[255], eb[255];
  int tid = threadIdx.x;
  if (tid < 255) { pb[tid] = pbins[tid]; eb[tid] = ebins[tid]; }
  __syncthreads();
  int g = blockIdx.x * 256 + tid;
  float pv = pt[g], ev = et[g];
  int lo = 0, hi = 255;
  while (lo < hi) { int md = (lo + hi) >> 1; if (pb[md] < pv) lo = md + 1; else hi = md; }
  int pi = lo;
  lo = 0; hi = 255;
  while (lo < hi) { int md = (lo + hi) >> 1; if (eb[md] < ev) lo = md + 1; else hi = md; }
  addrow[g] = pi | (lo << 16);
}

// ---------------------------------------------------------------------------
// Fused conv(k=3) GEMM + bias + ReLU + LN (+ linear head for mode=1).
// grid (512, 3); 4 waves, each 64 rows x 64 cols (4x4 MFMA 16x16x32 bf16).
// K-loop: direct global->VGPR fragment loads, 2-deep pipeline, NO barriers.
__global__ __launch_bounds__(256, 3) void k_conv(
    const char* __restrict__ Ab, size_t AperY, const char* __restrict__ Wb,
    const float* __restrict__ bias0, const float* __restrict__ gamma0,
    const float* __restrict__ beta0, char* __restrict__ hout0,
    const float* __restrict__ lw0, const float* __restrict__ lb0,
    const unsigned char* __restrict__ mask, float* __restrict__ outb,
    int mode) {
  __shared__ float redS[64][4];
  __shared__ float redS2[64][4];
  __shared__ float predr[64][4];

  int tid = threadIdx.x;
  int wv = tid >> 6;
  int ln = tid & 63;
  int q = ln >> 4;
  int m16 = ln & 15;
  int y = blockIdx.y;
  int g0 = blockIdx.x << 6;
  int t0 = g0 & (TSEQ - 1);

  const bf16* A = (const bf16*)(Ab + (size_t)y * AperY);
  const bf16* W = (const bf16*)(Wb + (size_t)y * WT_SZ);

  // per-mi A row pointer (dt=1 tap; dt-1 displacement folds into load offset)
  const bf16* PA[4];
#pragma unroll
  for (int mi = 0; mi < 4; ++mi)
    PA[mi] = A + ((size_t)(g0 + (mi << 4) + m16) << 8) + (q << 3);
  // per-ni B row pointer
  const bf16* PB[4];
#pragma unroll
  for (int ni = 0; ni < 4; ++ni)
    PB[ni] = W + (size_t)((wv << 6) + (ni << 4) + m16) * 768 + (q << 3);

  // conv boundary lanes: (t=-1 for dt=0, mi=0, m16=0 at t0==0) and
  // (t=1024 for dt=2, mi=3, m16=15 at t0==960). Guard bands make the loads
  // safe; these cndmasks make them zero.
  bool ez0 = (t0 == 0) && (m16 == 0);
  bool ez2 = (t0 == 960) && (m16 == 15);
  bf16x8 z8;
#pragma unroll
  for (int j = 0; j < 8; ++j) z8[j] = (bf16)0.f;

  f32x4 acc[4][4];
#pragma unroll
  for (int a = 0; a < 4; a++)
#pragma unroll
    for (int b = 0; b < 4; b++) acc[a][b] = (f32x4){0.f, 0.f, 0.f, 0.f};

  bf16x8 a_[2][4], b_[2][4];

#define LOADK(KB, BUF)                                                        \
  {                                                                           \
    int dt_ = (KB) >> 3;                                                      \
    int dispA_ = ((dt_ - 1) * 256 + ((KB) & 7) * 32) * 2;                     \
    _Pragma("unroll") for (int mi = 0; mi < 4; ++mi)                          \
        a_[BUF][mi] = *(const bf16x8*)((const char*)PA[mi] + dispA_);         \
    _Pragma("unroll") for (int ni = 0; ni < 4; ++ni)                          \
        b_[BUF][ni] = *(const bf16x8*)((const char*)PB[ni] + (KB) * 64);      \
    if ((KB) < 8 && ez0) a_[BUF][0] = z8;                                     \
    if ((KB) >= 16 && ez2) a_[BUF][3] = z8;                                   \
  }

  LOADK(0, 0);
#pragma unroll
  for (int kb = 0; kb < 24; ++kb) {
    int cur = kb & 1;
    if (kb < 23) LOADK(kb + 1, cur ^ 1);
#pragma unroll
    for (int mi = 0; mi < 4; mi++)
#pragma unroll
      for (int ni = 0; ni < 4; ni++)
        acc[mi][ni] = __builtin_amdgcn_mfma_f32_16x16x32_bf16(
            a_[cur][mi], b_[cur][ni], acc[mi][ni], 0, 0, 0);
  }
#undef LOADK

  // bias + ReLU + LN stats (cross-wave via LDS partials)
  const float* bias = bias0 + y * 256;
  const float* gamma = gamma0 + y * 256;
  const float* beta = beta0 + y * 256;
  float bias_v[4], g_v[4], be_v[4], lw_v[4];
#pragma unroll
  for (int ni = 0; ni < 4; ni++) {
    int nf = (wv << 6) + (ni << 4) + m16;
    bias_v[ni] = bias[nf];
    g_v[ni] = gamma[nf];
    be_v[ni] = beta[nf];
  }
  if (mode) {
    const float* lw = lw0 + y * 256;
#pragma unroll
    for (int ni = 0; ni < 4; ni++) lw_v[ni] = lw[(wv << 6) + (ni << 4) + m16];
  }

#pragma unroll
  for (int mi = 0; mi < 4; mi++) {
#pragma unroll
    for (int r = 0; r < 4; r++) {
      float s1 = 0.f, s2 = 0.f;
#pragma unroll
      for (int ni = 0; ni < 4; ni++) {
        float v = acc[mi][ni][r] + bias_v[ni];
        v = fmaxf(v, 0.f);
        acc[mi][ni][r] = v;
        s1 += v;
        s2 += v * v;
      }
#pragma unroll
      for (int d = 1; d < 16; d <<= 1) {
        s1 += __shfl_xor(s1, d);
        s2 += __shfl_xor(s2, d);
      }
      if (m16 == 0) {
        int m = (mi << 4) + (q << 2) + r;
        redS[m][wv] = s1;
        redS2[m][wv] = s2;
      }
    }
  }
  __syncthreads();

  if (mode == 0) {
    bf16* hp = (bf16*)(hout0 + (size_t)y * H1B_SZ);
#pragma unroll
    for (int mi = 0; mi < 4; mi++) {
#pragma unroll
      for (int r = 0; r < 4; r++) {
        int m = (mi << 4) + (q << 2) + r;
        float mu = (redS[m][0] + redS[m][1] + redS[m][2] + redS[m][3]) * 0.00390625f;
        float var = (redS2[m][0] + redS2[m][1] + redS2[m][2] + redS2[m][3]) * 0.00390625f - mu * mu;
        float rs = rsqrtf(var + 1e-5f);
        int gg = g0 + m;
#pragma unroll
        for (int ni = 0; ni < 4; ni++) {
          float v = (acc[mi][ni][r] - mu) * rs * g_v[ni] + be_v[ni];
          int n = (wv << 6) + (ni << 4) + m16;
          hp[((size_t)gg << 8) + n] = (bf16)v;
        }
      }
    }
  } else {
#pragma unroll
    for (int mi = 0; mi < 4; mi++) {
#pragma unroll
      for (int r = 0; r < 4; r++) {
        int m = (mi << 4) + (q << 2) + r;
        float mu = (redS[m][0] + redS[m][1] + redS[m][2] + redS[m][3]) * 0.00390625f;
        float var = (redS2[m][0] + redS2[m][1] + redS2[m][2] + redS2[m][3]) * 0.00390625f - mu * mu;
        float rs = rsqrtf(var + 1e-5f);
        float p = 0.f;
#pragma unroll
        for (int ni = 0; ni < 4; ni++) {
          float v = (acc[mi][ni][r] - mu) * rs * g_v[ni] + be_v[ni];
          p += v * lw_v[ni];
        }
#pragma unroll
        for (int d = 1; d < 16; d <<= 1) p += __shfl_xor(p, d);
        if (m16 == 0) predr[m][wv] = p;
      }
    }
    __syncthreads();
    if (tid < 64) {
      int gg = g0 + tid;
      float p = predr[tid][0] + predr[tid][1] + predr[tid][2] + predr[tid][3] + lb0[y];
      if (mask[gg]) p = 0.f;
      float* pd = outb + (y == 0 ? O3 : (y == 1 ? O1 : O2));
      pd[gg] = p;
    }
  }
}

// Length regulation. cum row cached in LDS; binary search is LDS-broadcast.
__global__ __launch_bounds__(256) void k_lr(const float* __restrict__ x,
                                            const int* __restrict__ cum,
                                            const int* __restrict__ addrow,
                                            const float* __restrict__ pemb,
                                            const float* __restrict__ eemb,
                                            const int* __restrict__ maxlen,
                                            float* __restrict__ outb) {
  __shared__ int cl[1024];
  int tid = threadIdx.x;
  int rid0 = blockIdx.x << 2;
  int b = rid0 >> 12;
  ((int4*)cl)[tid] = ((const int4*)(cum + (b << 10)))[tid];
  __syncthreads();
  int rid = rid0 + (tid >> 6);
  int lane = tid & 63;
  int j = rid & 4095;
  int total = cl[1023];
  int mel = total < maxlen[0] ? total : maxlen[0];
  bool valid = j < mel;
  float4 res = {0.f, 0.f, 0.f, 0.f};
  if (valid) {
    int lo = 0, hi = 1024;
    while (lo < hi) { int md = (lo + hi) >> 1; if (cl[md] <= j) lo = md + 1; else hi = md; }
    int i = lo < 1023 ? lo : 1023;
    int ar = addrow[(b << 10) + i];
    int pi = ar & 0xffff, ei = ar >> 16;
    const float4* xr = (const float4*)(x + (((size_t)(b << 10) + i) << 8));
    const float4* pr = (const float4*)(pemb + ((size_t)pi << 8));
    const float4* er = (const float4*)(eemb + ((size_t)ei << 8));
    float4 a = xr[lane], p = pr[lane], e = er[lane];
    res.x = a.x + p.x + e.x;
    res.y = a.y + p.y + e.y;
    res.z = a.z + p.z + e.z;
    res.w = a.w + p.w + e.w;
  }
  ((float4*)(outb + ((size_t)rid << 8)))[lane] = res;
  if (lane == 0) outb[O6 + rid] = valid ? 0.f : 1.f;
}

// ---------------------------------------------------------------------------
extern "C" void kernel_launch(void* const* d_in, const int* in_sizes, int n_in,
                              void* d_out, int out_size, void* d_ws, size_t ws_size,
                              hipStream_t stream) {
  const float* x = (const float*)d_in[0];
  const unsigned char* src_mask = (const unsigned char*)d_in[1];
  const int* dur = (const int*)d_in[2];
  const float* pt = (const float*)d_in[3];
  const float* et = (const float*)d_in[4];
  const int* maxlen = (const int*)d_in[5];
  const float* w1 = (const float*)d_in[6];
  const float* b1 = (const float*)d_in[7];
  const float* g1 = (const float*)d_in[8];
  const float* be1 = (const float*)d_in[9];
  const float* w2 = (const float*)d_in[10];
  const float* b2 = (const float*)d_in[11];
  const float* g2 = (const float*)d_in[12];
  const float* be2 = (const float*)d_in[13];
  const float* lw = (const float*)d_in[14];
  const float* lb = (const float*)d_in[15];
  const float* pbins = (const float*)d_in[16];
  const float* pemb = (const float*)d_in[17];
  const float* ebins = (const float*)d_in[18];
  const float* eemb = (const float*)d_in[19];

  float* outf = (float*)d_out;
  char* ob = (char*)d_out;
  bf16* xb = (bf16*)(ob + XB_OFF);
  char* h1b = ob + H1B_OFF;
  bf16* wt = (bf16*)(ob + WT_OFF);
  int* cum = (int*)((char*)d_ws + CUM_OFF);
  int* addrow = (int*)((char*)d_ws + ADDROW_OFF);

  hipLaunchKernelGGL(k_cvt_x, dim3(4096), dim3(256), 0, stream, x, xb);
  hipLaunchKernelGGL(k_cvt_w, dim3(4, 24, 6), dim3(256), 0, stream, w1, w2, wt);
  hipLaunchKernelGGL(k_bins, dim3(128), dim3(256), 0, stream, pt, et, pbins, ebins,
                     addrow);
  hipLaunchKernelGGL(k_scan, dim3(32), dim3(256), 0, stream, dur, maxlen, outf, cum);
  hipLaunchKernelGGL(k_conv, dim3(512, 3), dim3(256), 0, stream,
                     (const char*)xb, (size_t)0, (const char*)wt, b1, g1, be1, h1b,
                     lw, lb, src_mask, outf, 0);
  hipLaunchKernelGGL(k_conv, dim3(512, 3), dim3(256), 0, stream,
                     (const char*)h1b, (size_t)H1B_SZ,
                     (const char*)(ob + WT_OFF + 3 * WT_SZ), b2, g2, be2,
                     (char*)nullptr, lw, lb, src_mask, outf, 1);
  hipLaunchKernelGGL(k_lr, dim3(32768), dim3(256), 0, stream, x, cum, addrow, pemb,
                     eemb, maxlen, outf);
}

// Round 3
// 326.204 us; speedup vs baseline: 1.5671x; 1.5671x over previous
//
#include <hip/hip_runtime.h>
#include <hip/hip_bf16.h>
#include <stdint.h>

// ---------------------------------------------------------------------------
// VarianceAdaptor. Round 3: LDS-staged double-buffered MFMA conv.
// Block tile 128 rows x 256 cols, 4 waves, wave tile 64x128 (4x8 MFMA
// 16x16x32 bf16 => 32 MFMA per wave per K-chunk). global_load_lds width=16
// staging with source-side XOR swizzle (slot ^ (row>>1)&3) so fragment
// ds_read_b128 is a permutation of a contiguous 1KB => conflict-free.
// k_lr: 2-step 64-ary ballot search instead of 10-step binary search.
// ---------------------------------------------------------------------------

typedef __bf16 bf16;
typedef __attribute__((ext_vector_type(8))) __bf16 bf16x8;
typedef __attribute__((ext_vector_type(4))) float f32x4;

#define TSEQ 1024

// output chunk offsets (floats)
#define O1 33554432          // pitch_pred
#define O2 33587200          // energy_pred
#define O3 33619968          // log_dur
#define O4 33652736          // duration passthrough
#define O5 33685504          // mel_len
#define O6 33685536          // mel_mask

// scratch byte offsets inside d_out
#define XB_OFF 512
#define H1B_OFF (XB_OFF + 16777216)
#define H1B_SZ 16777216
#define WT_OFF (H1B_OFF + 3 * H1B_SZ)
#define WT_SZ 393216

// ws byte offsets
#define CUM_OFF 0
#define ADDROW_OFF 131072
#define ZEROS_OFF 262144

// ---------------------------------------------------------------------------
// Fused prep: [0,4096) cvt_x | [4096,4672) cvt_w | [4672,4800) bins+zpage |
// [4800,4832) scan. All independent; consumed by later dispatches.
__global__ __launch_bounds__(256) void k_prep(
    const float* __restrict__ x, bf16* __restrict__ xb,
    const float* __restrict__ w1, const float* __restrict__ w2,
    bf16* __restrict__ wt,
    const float* __restrict__ pt, const float* __restrict__ et,
    const float* __restrict__ pbins, const float* __restrict__ ebins,
    int* __restrict__ addrow, float* __restrict__ zpage,
    const int* __restrict__ dur, const int* __restrict__ maxlen,
    float* __restrict__ out, int* __restrict__ cum) {
  int bid = blockIdx.x;
  int tid = threadIdx.x;
  if (bid < 4096) {
    // fp32 -> bf16 copy of x (plain row-major, 256 ch/row)
    int t = bid * 256 + tid;
    int g = t >> 5;
    int u = t & 31;
    const float4* s = (const float4*)(x + ((size_t)g << 8) + (u << 3));
    float4 a = s[0], b = s[1];
    bf16x8 o;
    o[0] = (bf16)a.x; o[1] = (bf16)a.y; o[2] = (bf16)a.z; o[3] = (bf16)a.w;
    o[4] = (bf16)b.x; o[5] = (bf16)b.y; o[6] = (bf16)b.z; o[7] = (bf16)b.w;
    *(bf16x8*)(xb + ((size_t)g << 8) + (u << 3)) = o;
  } else if (bid < 4672) {
    // (3,K,H,F) WIO fp32 -> wT[m][f][k] bf16 (k = dt*256 + c)
    int bw = bid - 4096;
    int m = bw / 96;
    int r = bw % 96;
    int f = (r & 3) * 64 + (tid & 63);
    int u = (r >> 2) * 4 + (tid >> 6);
    const float* W = (m < 3) ? w1 : w2;
    int i = (m < 3) ? m : m - 3;
    int dt = u >> 5;
    int c0 = (u & 31) << 3;
    const float* src = W + (((size_t)(i * 3 + dt) * 256 + c0) << 8) + f;
    bf16x8 o;
#pragma unroll
    for (int cc = 0; cc < 8; ++cc) o[cc] = (bf16)src[(size_t)cc << 8];
    *(bf16x8*)(wt + (size_t)m * 196608 + (size_t)f * 768 + (u << 3)) = o;
  } else if (bid < 4800) {
    // searchsorted(left) of pitch/energy targets into bins; zero the zpage
    __shared__ float pb[255], eb[255];
    if (tid < 255) { pb[tid] = pbins[tid]; eb[tid] = ebins[tid]; }
    if (bid == 4672 && tid < 64) zpage[tid] = 0.f;
    __syncthreads();
    int g = (bid - 4672) * 256 + tid;
    float pv = pt[g], ev = et[g];
    int lo = 0, hi = 255;
    while (lo < hi) { int md = (lo + hi) >> 1; if (pb[md] < pv) lo = md + 1; else hi = md; }
    int pi = lo;
    lo = 0; hi = 255;
    while (lo < hi) { int md = (lo + hi) >> 1; if (eb[md] < ev) lo = md + 1; else hi = md; }
    addrow[g] = pi | (lo << 16);
  } else {
    // cumsum(dur) + mel_len + duration passthrough
    __shared__ int lds[256];
    int b = bid - 4800;
    int4 d = ((const int4*)(dur + b * 1024))[tid];
    int p0 = d.x, p1 = p0 + d.y, p2 = p1 + d.z, p3 = p2 + d.w;
    int val = p3;
    lds[tid] = val;
    __syncthreads();
    for (int off = 1; off < 256; off <<= 1) {
      int t = (tid >= off) ? lds[tid - off] : 0;
      __syncthreads();
      val += t;
      lds[tid] = val;
      __syncthreads();
    }
    int excl = val - p3;
    int4 c;
    c.x = excl + p0; c.y = excl + p1; c.z = excl + p2; c.w = excl + p3;
    ((int4*)(cum + b * 1024))[tid] = c;
    float4 fd;
    fd.x = (float)d.x; fd.y = (float)d.y; fd.z = (float)d.z; fd.w = (float)d.w;
    ((float4*)(out + O4 + b * 1024))[tid] = fd;
    if (tid == 255) {
      int mel = val < maxlen[0] ? val : maxlen[0];
      out[O5 + b] = (float)mel;
    }
  }
}

// ---------------------------------------------------------------------------
// Fused conv(k=3) GEMM + bias + ReLU + LN (+ linear head for mode=1).
// grid (256, 3); 4 waves; wave (rh,ch) computes rows rh*64+[0,64) x cols
// ch*128+[0,128). Double-buffered LDS, global_load_lds width=16.
__global__ __launch_bounds__(256, 2) void k_conv(
    const char* __restrict__ Ab, size_t AperY, const char* __restrict__ Wb,
    const float* __restrict__ bias0, const float* __restrict__ gamma0,
    const float* __restrict__ beta0, char* __restrict__ hout0,
    const float* __restrict__ lw0, const float* __restrict__ lb0,
    const unsigned char* __restrict__ mask, float* __restrict__ outb,
    const char* __restrict__ zpage, int mode) {
  __shared__ __align__(16) char Abuf[2][8192];    // 128 rows x 64B
  __shared__ __align__(16) char Bbuf[2][16384];   // 256 f x 64B
  __shared__ float redS[128][2];
  __shared__ float redS2[128][2];
  __shared__ float predr[128][2];

  const int tid = threadIdx.x;
  const int wv = tid >> 6;
  const int ln = tid & 63;
  const int q = ln >> 4;
  const int m16 = ln & 15;
  const int rh = wv >> 1;
  const int ch = wv & 1;
  const int y = blockIdx.y;
  const int g0 = blockIdx.x << 7;
  const int t0 = g0 & (TSEQ - 1);

  const char* A = Ab + (size_t)y * AperY;
  const char* W = Wb + (size_t)y * WT_SZ;

  // staging lane geometry: thread covers (row = j*64 + wv*16 + srow, slot)
  const int srow = ln >> 2;
  const int slot = ln & 3;
  const int usw = slot ^ ((ln >> 3) & 3);   // source-side XOR swizzle

  // B source base per staging instruction j (f = j*64 + wv*16 + srow)
  const char* bsrc[4];
#pragma unroll
  for (int j = 0; j < 4; ++j) {
    int f = j * 64 + wv * 16 + srow;
    bsrc[j] = W + ((size_t)f * 768 + usw * 8) * 2;
  }
  const int rbase = wv * 16 + srow;   // A staging row base (j adds 64)

  f32x4 acc[4][8];
#pragma unroll
  for (int a = 0; a < 4; a++)
#pragma unroll
    for (int b = 0; b < 8; b++) acc[a][b] = (f32x4){0.f, 0.f, 0.f, 0.f};

#define STAGE(KB, BUF)                                                         \
  {                                                                            \
    int dt0_ = (KB) >> 3;                                                      \
    int c0_ = ((KB) & 7) << 5;                                                 \
    _Pragma("unroll") for (int j = 0; j < 2; ++j) {                            \
      int rr = j * 64 + rbase + dt0_ - 1;                                      \
      const char* src = ((unsigned)(t0 + rr) < 1024u)                          \
          ? A + (((size_t)(g0 + rr) << 8) + c0_ + usw * 8) * 2                 \
          : zpage + slot * 16;                                                 \
      __builtin_amdgcn_global_load_lds(                                        \
          (const __attribute__((address_space(1))) void*)src,                  \
          (__attribute__((address_space(3))) void*)(Abuf[BUF] + j * 4096 +     \
                                                    tid * 16),                 \
          16, 0, 0);                                                           \
    }                                                                          \
    _Pragma("unroll") for (int j = 0; j < 4; ++j) {                            \
      __builtin_amdgcn_global_load_lds(                                        \
          (const __attribute__((address_space(1))) void*)(bsrc[j] + (KB)*64),  \
          (__attribute__((address_space(3))) void*)(Bbuf[BUF] + j * 4096 +     \
                                                    tid * 16),                 \
          16, 0, 0);                                                           \
    }                                                                          \
  }

  const int spq = (q ^ ((m16 >> 1) & 3)) << 4;   // fragment slot bytes
  const int aoff = (rh * 64 + m16) * 64 + spq;
  const int boff = (ch * 128 + m16) * 64 + spq;

  STAGE(0, 0);
#pragma unroll 2
  for (int kb = 0; kb < 24; ++kb) {
    int buf = kb & 1;
    __syncthreads();
    if (kb < 23) STAGE(kb + 1, buf ^ 1);
    bf16x8 af[4], bfr[8];
#pragma unroll
    for (int mi = 0; mi < 4; ++mi)
      af[mi] = *(const bf16x8*)(Abuf[buf] + aoff + mi * 1024);
#pragma unroll
    for (int ni = 0; ni < 8; ++ni)
      bfr[ni] = *(const bf16x8*)(Bbuf[buf] + boff + ni * 1024);
#pragma unroll
    for (int mi = 0; mi < 4; ++mi)
#pragma unroll
      for (int ni = 0; ni < 8; ++ni)
        acc[mi][ni] = __builtin_amdgcn_mfma_f32_16x16x32_bf16(
            af[mi], bfr[ni], acc[mi][ni], 0, 0, 0);
  }
#undef STAGE

  // bias + ReLU + LN stats (row partials per col-half into LDS)
  const float* bias = bias0 + y * 256;
  const float* gamma = gamma0 + y * 256;
  const float* beta = beta0 + y * 256;
  float bias_v[8], g_v[8], be_v[8], lw_v[8];
#pragma unroll
  for (int ni = 0; ni < 8; ni++) {
    int nf = (ch << 7) + (ni << 4) + m16;
    bias_v[ni] = bias[nf];
    g_v[ni] = gamma[nf];
    be_v[ni] = beta[nf];
  }
  if (mode) {
    const float* lw = lw0 + y * 256;
#pragma unroll
    for (int ni = 0; ni < 8; ni++) lw_v[ni] = lw[(ch << 7) + (ni << 4) + m16];
  }

#pragma unroll
  for (int mi = 0; mi < 4; mi++) {
#pragma unroll
    for (int r = 0; r < 4; r++) {
      float s1 = 0.f, s2 = 0.f;
#pragma unroll
      for (int ni = 0; ni < 8; ni++) {
        float v = acc[mi][ni][r] + bias_v[ni];
        v = fmaxf(v, 0.f);
        acc[mi][ni][r] = v;
        s1 += v;
        s2 += v * v;
      }
#pragma unroll
      for (int d = 1; d < 16; d <<= 1) {
        s1 += __shfl_xor(s1, d);
        s2 += __shfl_xor(s2, d);
      }
      if (m16 == 0) {
        int m = (rh << 6) + (mi << 4) + (q << 2) + r;
        redS[m][ch] = s1;
        redS2[m][ch] = s2;
      }
    }
  }
  __syncthreads();

  if (mode == 0) {
    bf16* hp = (bf16*)(hout0 + (size_t)y * H1B_SZ);
#pragma unroll
    for (int mi = 0; mi < 4; mi++) {
#pragma unroll
      for (int r = 0; r < 4; r++) {
        int m = (rh << 6) + (mi << 4) + (q << 2) + r;
        float mu = (redS[m][0] + redS[m][1]) * 0.00390625f;
        float var = (redS2[m][0] + redS2[m][1]) * 0.00390625f - mu * mu;
        float rs = rsqrtf(var + 1e-5f);
        int gg = g0 + m;
#pragma unroll
        for (int ni = 0; ni < 8; ni++) {
          float v = (acc[mi][ni][r] - mu) * rs * g_v[ni] + be_v[ni];
          int n = (ch << 7) + (ni << 4) + m16;
          hp[((size_t)gg << 8) + n] = (bf16)v;
        }
      }
    }
  } else {
#pragma unroll
    for (int mi = 0; mi < 4; mi++) {
#pragma unroll
      for (int r = 0; r < 4; r++) {
        int m = (rh << 6) + (mi << 4) + (q << 2) + r;
        float mu = (redS[m][0] + redS[m][1]) * 0.00390625f;
        float var = (redS2[m][0] + redS2[m][1]) * 0.00390625f - mu * mu;
        float rs = rsqrtf(var + 1e-5f);
        float p = 0.f;
#pragma unroll
        for (int ni = 0; ni < 8; ni++) {
          float v = (acc[mi][ni][r] - mu) * rs * g_v[ni] + be_v[ni];
          p += v * lw_v[ni];
        }
#pragma unroll
        for (int d = 1; d < 16; d <<= 1) p += __shfl_xor(p, d);
        if (m16 == 0) predr[m][ch] = p;
      }
    }
    __syncthreads();
    if (tid < 128) {
      int gg = g0 + tid;
      float p = predr[tid][0] + predr[tid][1] + lb0[y];
      if (mask[gg]) p = 0.f;
      float* pd = outb + (y == 0 ? O3 : (y == 1 ? O1 : O2));
      pd[gg] = p;
    }
  }
}

// ---------------------------------------------------------------------------
// Length regulation. 16 rows/block; cum row in LDS; per-row phoneme lookup
// via 2-step 64-ary ballot search (no serial binary search).
__global__ __launch_bounds__(256) void k_lr(const float* __restrict__ x,
                                            const int* __restrict__ cum,
                                            const int* __restrict__ addrow,
                                            const float* __restrict__ pemb,
                                            const float* __restrict__ eemb,
                                            const int* __restrict__ maxlen,
                                            float* __restrict__ outb) {
  __shared__ int cl[1024];
  int tid = threadIdx.x;
  int rid0 = blockIdx.x << 4;          // 16 rows per block
  int b = rid0 >> 12;
  ((int4*)cl)[tid] = ((const int4*)(cum + (b << 10)))[tid];
  __syncthreads();
  int lane = tid & 63;
  int wv = tid >> 6;
  int total = cl[1023];
  int ml = maxlen[0];
  int mel = total < ml ? total : ml;
  int c1 = cl[lane * 16 + 15];         // segment maxima for level-1 search
#pragma unroll
  for (int rr = 0; rr < 4; ++rr) {
    int rid = rid0 + (wv << 2) + rr;
    int j = rid & 4095;
    bool valid = j < mel;
    float4 res = {0.f, 0.f, 0.f, 0.f};
    if (valid) {
      unsigned long long m1 = __ballot(j < c1);
      int s = __ffsll(m1) - 1;
      unsigned long long m2 = __ballot(j < cl[s * 16 + (lane & 15)]);
      int p = __ffsll(m2) - 1;
      int i = s * 16 + p;
      int ar = addrow[(b << 10) + i];
      int pi = ar & 0xffff, ei = ar >> 16;
      const float4* xr = (const float4*)(x + (((size_t)(b << 10) + i) << 8));
      const float4* pr = (const float4*)(pemb + ((size_t)pi << 8));
      const float4* er = (const float4*)(eemb + ((size_t)ei << 8));
      float4 a = xr[lane], pp = pr[lane], e = er[lane];
      res.x = a.x + pp.x + e.x;
      res.y = a.y + pp.y + e.y;
      res.z = a.z + pp.z + e.z;
      res.w = a.w + pp.w + e.w;
    }
    ((float4*)(outb + ((size_t)rid << 8)))[lane] = res;
    if (lane == 0) outb[O6 + rid] = valid ? 0.f : 1.f;
  }
}

// ---------------------------------------------------------------------------
extern "C" void kernel_launch(void* const* d_in, const int* in_sizes, int n_in,
                              void* d_out, int out_size, void* d_ws, size_t ws_size,
                              hipStream_t stream) {
  const float* x = (const float*)d_in[0];
  const unsigned char* src_mask = (const unsigned char*)d_in[1];
  const int* dur = (const int*)d_in[2];
  const float* pt = (const float*)d_in[3];
  const float* et = (const float*)d_in[4];
  const int* maxlen = (const int*)d_in[5];
  const float* w1 = (const float*)d_in[6];
  const float* b1 = (const float*)d_in[7];
  const float* g1 = (const float*)d_in[8];
  const float* be1 = (const float*)d_in[9];
  const float* w2 = (const float*)d_in[10];
  const float* b2 = (const float*)d_in[11];
  const float* g2 = (const float*)d_in[12];
  const float* be2 = (const float*)d_in[13];
  const float* lw = (const float*)d_in[14];
  const float* lb = (const float*)d_in[15];
  const float* pbins = (const float*)d_in[16];
  const float* pemb = (const float*)d_in[17];
  const float* ebins = (const float*)d_in[18];
  const float* eemb = (const float*)d_in[19];

  float* outf = (float*)d_out;
  char* ob = (char*)d_out;
  bf16* xb = (bf16*)(ob + XB_OFF);
  char* h1b = ob + H1B_OFF;
  bf16* wt = (bf16*)(ob + WT_OFF);
  int* cum = (int*)((char*)d_ws + CUM_OFF);
  int* addrow = (int*)((char*)d_ws + ADDROW_OFF);
  float* zpage = (float*)((char*)d_ws + ZEROS_OFF);

  hipLaunchKernelGGL(k_prep, dim3(4832), dim3(256), 0, stream,
                     x, xb, w1, w2, wt, pt, et, pbins, ebins, addrow, zpage,
                     dur, maxlen, outf, cum);
  hipLaunchKernelGGL(k_conv, dim3(256, 3), dim3(256), 0, stream,
                     (const char*)xb, (size_t)0, (const char*)wt, b1, g1, be1,
                     h1b, lw, lb, src_mask, outf, (const char*)zpage, 0);
  hipLaunchKernelGGL(k_conv, dim3(256, 3), dim3(256), 0, stream,
                     (const char*)h1b, (size_t)H1B_SZ,
                     (const char*)(ob + WT_OFF + 3 * WT_SZ), b2, g2, be2,
                     (char*)nullptr, lw, lb, src_mask, outf,
                     (const char*)zpage, 1);
  hipLaunchKernelGGL(k_lr, dim3(2048), dim3(256), 0, stream, x, cum, addrow,
                     pemb, eemb, maxlen, outf);
}